// Round 4
// baseline (147.978 us; speedup 1.0000x reference)
//
#include <hip/hip_runtime.h>
#include <hip/hip_cooperative_groups.h>

namespace cg = cooperative_groups;

// SoftRAMAttention — S=2048, B=64, H=8, K=12, N_POS=11
//
// addr[i,j,h] = addr_q[i,h] | addr_k[j,h] | addr_p[i-j,h]  (disjoint bit groups)
// votes[i,j]  = sum_h head_table_bit[h][addr]   (head_table is 0/1 -> bit-packed)
// out[i,:]    = max_{j<=i} votes > 0 ? table_v[:, addr_v[argmax]] : 0
//
// R4: single cooperative kernel (precompute -> grid.sync -> vote) to drop one
//     dispatch; parity-slot done flags -> one barrier per 256-col chunk.
//     Addresses packed 8 x u16 per row (uint4); early exit on v==8.

#define SS 2048
#define BB 64
#define HH 8
#define KK 12
#define NPOS 11
#define TBL 4096           // 1 << KK
#define TBLW (TBL / 32)    // 128 words per head

typedef unsigned short u16;
typedef unsigned int u32;

// two packed 12-bit addrs per 32-bit word; heads (2w, 2w+1)
__device__ __forceinline__ int votes_packed(const u32* sbits,
                                            const uint4& q, const uint4& kk, const uint4& pp)
{
    int v = 0;
    u32 w, a0, a1;
    w = q.x | kk.x | pp.x;
    a0 = w & 0xFFFFu; a1 = w >> 16;
    v += (sbits[0 * TBLW + (a0 >> 5)] >> (a0 & 31)) & 1;
    v += (sbits[1 * TBLW + (a1 >> 5)] >> (a1 & 31)) & 1;
    w = q.y | kk.y | pp.y;
    a0 = w & 0xFFFFu; a1 = w >> 16;
    v += (sbits[2 * TBLW + (a0 >> 5)] >> (a0 & 31)) & 1;
    v += (sbits[3 * TBLW + (a1 >> 5)] >> (a1 & 31)) & 1;
    w = q.z | kk.z | pp.z;
    a0 = w & 0xFFFFu; a1 = w >> 16;
    v += (sbits[4 * TBLW + (a0 >> 5)] >> (a0 & 31)) & 1;
    v += (sbits[5 * TBLW + (a1 >> 5)] >> (a1 & 31)) & 1;
    w = q.w | kk.w | pp.w;
    a0 = w & 0xFFFFu; a1 = w >> 16;
    v += (sbits[6 * TBLW + (a0 >> 5)] >> (a0 & 31)) & 1;
    v += (sbits[7 * TBLW + (a1 >> 5)] >> (a1 & 31)) & 1;
    return v;
}

__global__ __launch_bounds__(256, 4) void fused_kernel(
    const int* __restrict__ tokens,        // (S,B) values {0,1}
    const int* __restrict__ conn_heads,    // (H,K)
    const float* __restrict__ head_table,  // (H,4096) values {0.0,1.0}
    const int* __restrict__ conn_v,        // (B,K)
    const float* __restrict__ table_v,     // (B,4096)
    u16* __restrict__ A16, u16* __restrict__ AK16, u16* __restrict__ P16,
    u32* __restrict__ bits_g,
    float* __restrict__ out)               // (S,B) fp32
{
    const int tid = threadIdx.x;
    const int b = blockIdx.x;

    // ---------------- phase 1: precompute addr tables + packed bits ----------
    {
        int gid = b * 256 + tid;
        if (gid < SS * HH) {
            int s = gid >> 3;
            int h = gid & 7;
            int aq = 0, ak = 0, ap = 0;
            #pragma unroll
            for (int k = 0; k < KK; ++k) {
                int c = conn_heads[h * KK + k];
                int sh = KK - 1 - k;
                if (c < BB) {
                    aq |= (tokens[s * BB + c] & 1) << sh;
                } else if (c < 2 * BB) {
                    ak |= (tokens[s * BB + (c - BB)] & 1) << sh;
                } else {
                    int cp = c - 2 * BB;              // in [0, NPOS)
                    ap |= ((s >> (NPOS - 1 - cp)) & 1) << sh;
                }
            }
            A16[gid]  = (u16)aq;
            AK16[gid] = (u16)ak;
            P16[gid]  = (u16)ap;
        } else if (gid < SS * HH + HH * TBLW) {
            int w = gid - SS * HH;
            int h = w >> 7;
            int wi = w & (TBLW - 1);
            u32 bv = 0;
            #pragma unroll
            for (int bb = 0; bb < 32; ++bb) {
                if (head_table[h * TBL + wi * 32 + bb] > 0.5f) bv |= (1u << bb);
            }
            bits_g[w] = bv;
        }
    }

    cg::this_grid().sync();   // device-scope fence + grid barrier

    // ---------------- phase 2: vote scan, rows (b, S-1-b) -------------------
    __shared__ u32 sbits[HH * TBLW];   // 4 KB
    __shared__ u32 skey[2][4];
    __shared__ int sdone[2][2];        // [row][chunk parity]

    const int i0 = b;             // short row (i0 <= 1023)
    const int i1 = SS - 1 - b;    // long row  (i1 >= 1024)

    ((uint4*)sbits)[tid] = ((const uint4*)bits_g)[tid];   // 256 x 16B = 4 KB
    if (tid < 4) ((int*)sdone)[tid] = 0;
    __syncthreads();

    const uint4 q0 = *(const uint4*)(A16 + i0 * HH);
    const uint4 q1 = *(const uint4*)(A16 + i1 * HH);

    // key = (v << 12) | (4095 - j): max key == max v, tie -> smallest j.
    // key 0 == "nothing visited"; any visited column yields key >= 2048.
    u32 key0 = 0u, key1 = 0u;
    int done0 = 0, done1 = 0;
    const int nc0 = (i0 >> 8) + 1;   // 256-col chunks for row0
    const int nc1 = (i1 >> 8) + 1;

    for (int c = 0; ; ++c) {
        const int j = (c << 8) + tid;
        const int par = c & 1;
        int f0 = 0, f1 = 0;
        if (!done0 && j <= i0) {
            const uint4 kk = *(const uint4*)(AK16 + j * HH);
            const uint4 pp = *(const uint4*)(P16 + (i0 - j) * HH);
            int v = votes_packed(sbits, q0, kk, pp);
            u32 key = ((u32)v << 12) | (u32)(4095 - j);
            key0 = key0 > key ? key0 : key;
            f0 = (v == HH);
        }
        if (!done1 && j <= i1) {
            const uint4 kk = *(const uint4*)(AK16 + j * HH);
            const uint4 pp = *(const uint4*)(P16 + (i1 - j) * HH);
            int v = votes_packed(sbits, q1, kk, pp);
            u32 key = ((u32)v << 12) | (u32)(4095 - j);
            key1 = key1 > key ? key1 : key;
            f1 = (v == HH);
        }
        if (f0) sdone[0][par] = 1;
        if (f1) sdone[1][par] = 1;
        __syncthreads();
        // chunk c+1 writes the other parity slot; next write to THIS slot is
        // at chunk c+2, separated from these reads by barrier(c+1) -> no race.
        done0 |= sdone[0][par] | ((c + 1) >= nc0);
        done1 |= sdone[1][par] | ((c + 1) >= nc1);
        if (done0 && done1) break;
    }

    // 64-lane butterfly max for both rows (no barriers)
    #pragma unroll
    for (int off = 32; off > 0; off >>= 1) {
        u32 o0 = (u32)__shfl_xor((int)key0, off, 64);
        u32 o1 = (u32)__shfl_xor((int)key1, off, 64);
        key0 = key0 > o0 ? key0 : o0;
        key1 = key1 > o1 ? key1 : o1;
    }
    if ((tid & 63) == 0) {
        skey[0][tid >> 6] = key0;
        skey[1][tid >> 6] = key1;
    }
    __syncthreads();

    // threads 0..63 emit row i0, threads 64..127 emit row i1
    if (tid < 128) {
        const int r = tid >> 6;
        const int lane = tid & 63;
        u32 ka = skey[r][0] > skey[r][1] ? skey[r][0] : skey[r][1];
        u32 kb = skey[r][2] > skey[r][3] ? skey[r][2] : skey[r][3];
        u32 kf = ka > kb ? ka : kb;
        const int row = r ? i1 : i0;
        float o = 0.0f;
        if ((kf >> 12) > 0) {
            const int best = 4095 - (int)(kf & 4095u);
            int av = 0;
            #pragma unroll
            for (int k = 0; k < KK; ++k) {
                int c = conn_v[lane * KK + k];
                av |= (tokens[best * BB + c] & 1) << (KK - 1 - k);
            }
            o = table_v[lane * TBL + av];
        }
        out[row * BB + lane] = o;
    }
}

extern "C" void kernel_launch(void* const* d_in, const int* in_sizes, int n_in,
                              void* d_out, int out_size, void* d_ws, size_t ws_size,
                              hipStream_t stream) {
    const int*   tokens     = (const int*)d_in[0];
    const int*   conn_heads = (const int*)d_in[1];
    const float* head_table = (const float*)d_in[2];
    const int*   conn_v     = (const int*)d_in[3];
    const float* table_v    = (const float*)d_in[4];
    float* out = (float*)d_out;

    int* ws = (int*)d_ws;
    u16* A16  = (u16*)ws;                         // S*8 u16 = 8192 ints
    u16* AK16 = (u16*)(ws + 1 * SS * HH / 2);
    u16* P16  = (u16*)(ws + 2 * SS * HH / 2);
    u32* bits = (u32*)(ws + 3 * SS * HH / 2);

    void* args[] = {
        (void*)&tokens, (void*)&conn_heads, (void*)&head_table,
        (void*)&conn_v, (void*)&table_v,
        (void*)&A16, (void*)&AK16, (void*)&P16, (void*)&bits,
        (void*)&out
    };
    hipLaunchCooperativeKernel((void*)fused_kernel, dim3(SS / 2), dim3(256),
                               args, 0, stream);
}

// Round 5
// 72.322 us; speedup vs baseline: 2.0461x; 2.0461x over previous
//
#include <hip/hip_runtime.h>

// SoftRAMAttention — S=2048, B=64, H=8, K=12, N_POS=11
//
// addr[i,j,h] = addr_q[i,h] | addr_k[j,h] | addr_p[i-j,h]  (disjoint bit groups)
// votes[i,j]  = sum_h head_table_bit[h][addr]   (head_table is 0/1 -> bit-packed)
// out[i,:]    = max_{j<=i} votes > 0 ? table_v[:, addr_v[argmax]] : 0
//
// R5: back to two regular launches (grid.sync over 8 XCDs cost ~40 µs — R4).
//     Vote loop is now a FIXED-TRIP (8 iter) barrier-free scan: rows (b,2047-b)
//     give exactly 2049 columns; flat column c -> (row, j) by compare. All
//     iterations independent -> software-pipelined loads, no per-chunk
//     barriers (R3/R4's done-flag + syncthreads protocol was the stall).

#define SS 2048
#define BB 64
#define HH 8
#define KK 12
#define NPOS 11
#define TBL 4096           // 1 << KK
#define TBLW (TBL / 32)    // 128 words per head

typedef unsigned short u16;
typedef unsigned int u32;

__global__ __launch_bounds__(256) void precompute_kernel(
    const int* __restrict__ tokens,        // (S,B) values {0,1}
    const int* __restrict__ conn_heads,    // (H,K)
    const float* __restrict__ head_table,  // (H,4096) values {0.0,1.0}
    u16* __restrict__ A16, u16* __restrict__ AK16, u16* __restrict__ P16,
    u32* __restrict__ bits)
{
    int gid = blockIdx.x * blockDim.x + threadIdx.x;
    if (gid < SS * HH) {
        int s = gid >> 3;
        int h = gid & 7;
        int aq = 0, ak = 0, ap = 0;
        #pragma unroll
        for (int k = 0; k < KK; ++k) {
            int c = conn_heads[h * KK + k];
            int sh = KK - 1 - k;
            if (c < BB) {
                aq |= (tokens[s * BB + c] & 1) << sh;
            } else if (c < 2 * BB) {
                ak |= (tokens[s * BB + (c - BB)] & 1) << sh;
            } else {
                int cp = c - 2 * BB;              // in [0, NPOS)
                ap |= ((s >> (NPOS - 1 - cp)) & 1) << sh;
            }
        }
        A16[gid]  = (u16)aq;
        AK16[gid] = (u16)ak;
        P16[gid]  = (u16)ap;
    } else {
        int w = gid - SS * HH;
        if (w < HH * TBLW) {
            int h = w >> 7;
            int wi = w & (TBLW - 1);
            u32 bv = 0;
            #pragma unroll
            for (int b = 0; b < 32; ++b) {
                if (head_table[h * TBL + wi * 32 + b] > 0.5f) bv |= (1u << b);
            }
            bits[w] = bv;
        }
    }
}

// two packed 12-bit addrs per 32-bit word; heads (2w, 2w+1)
__device__ __forceinline__ int votes_packed(const u32* sbits,
                                            const uint4& q, const uint4& kk, const uint4& pp)
{
    int v = 0;
    u32 w, a0, a1;
    w = q.x | kk.x | pp.x;
    a0 = w & 0xFFFFu; a1 = w >> 16;
    v += (sbits[0 * TBLW + (a0 >> 5)] >> (a0 & 31)) & 1;
    v += (sbits[1 * TBLW + (a1 >> 5)] >> (a1 & 31)) & 1;
    w = q.y | kk.y | pp.y;
    a0 = w & 0xFFFFu; a1 = w >> 16;
    v += (sbits[2 * TBLW + (a0 >> 5)] >> (a0 & 31)) & 1;
    v += (sbits[3 * TBLW + (a1 >> 5)] >> (a1 & 31)) & 1;
    w = q.z | kk.z | pp.z;
    a0 = w & 0xFFFFu; a1 = w >> 16;
    v += (sbits[4 * TBLW + (a0 >> 5)] >> (a0 & 31)) & 1;
    v += (sbits[5 * TBLW + (a1 >> 5)] >> (a1 & 31)) & 1;
    w = q.w | kk.w | pp.w;
    a0 = w & 0xFFFFu; a1 = w >> 16;
    v += (sbits[6 * TBLW + (a0 >> 5)] >> (a0 & 31)) & 1;
    v += (sbits[7 * TBLW + (a1 >> 5)] >> (a1 & 31)) & 1;
    return v;
}

__global__ __launch_bounds__(256) void vote_kernel(
    const u16* __restrict__ A16, const u16* __restrict__ AK16, const u16* __restrict__ P16,
    const u32* __restrict__ bits_g,
    const int* __restrict__ tokens,     // (S,B)
    const int* __restrict__ conn_v,     // (B,K)
    const float* __restrict__ table_v,  // (B,4096)
    float* __restrict__ out)            // (S,B) fp32
{
    __shared__ u32 sbits[HH * TBLW];   // 4 KB
    __shared__ u32 skey[2][4];

    const int tid = threadIdx.x;
    const int b = blockIdx.x;
    const int i0 = b;             // short row (i0 <= 1023)
    const int i1 = SS - 1 - b;    // long row  (i1 >= 1024)

    ((uint4*)sbits)[tid] = ((const uint4*)bits_g)[tid];   // 256 x 16B = 4 KB
    __syncthreads();

    const uint4 q0 = *(const uint4*)(A16 + i0 * HH);
    const uint4 q1 = *(const uint4*)(A16 + i1 * HH);

    // key = (v << 12) | (4095 - j): max key == max v, tie -> smallest j.
    // key 0 == "nothing visited"; any visited column yields key >= 2048.
    u32 key0 = 0u, key1 = 0u;

    // rows (i0, i1) have (i0+1) + (i1+1) = 2049 columns total.
    // flat c in [0,2048): c <= i0 -> (row i0, j=c); else (row i1, j=c-i0-1).
    // all 8 iterations independent -> pipelined; no barriers.
    #pragma unroll
    for (int it = 0; it < 8; ++it) {
        const int c = (it << 8) + tid;
        const bool r0 = (c <= i0);
        const int j = r0 ? c : (c - i0 - 1);       // row-local column
        const int d = r0 ? (i0 - c) : (2048 - c);  // i - j for that row
        const uint4 kk = *(const uint4*)(AK16 + j * HH);
        const uint4 pp = *(const uint4*)(P16 + d * HH);
        const uint4 q = r0 ? q0 : q1;
        const int v = votes_packed(sbits, q, kk, pp);
        const u32 key = ((u32)v << 12) | (u32)(4095 - j);
        if (r0) { key0 = key0 > key ? key0 : key; }
        else    { key1 = key1 > key ? key1 : key; }
    }
    if (tid == 0) {   // straggler c = 2048 -> row i1, j = i1, d = 0
        const uint4 kk = *(const uint4*)(AK16 + i1 * HH);
        const uint4 pp = *(const uint4*)(P16);
        const int v = votes_packed(sbits, q1, kk, pp);
        const u32 key = ((u32)v << 12) | (u32)(4095 - i1);
        key1 = key1 > key ? key1 : key;
    }

    // 64-lane butterfly max for both rows (no barriers)
    #pragma unroll
    for (int off = 32; off > 0; off >>= 1) {
        u32 o0 = (u32)__shfl_xor((int)key0, off, 64);
        u32 o1 = (u32)__shfl_xor((int)key1, off, 64);
        key0 = key0 > o0 ? key0 : o0;
        key1 = key1 > o1 ? key1 : o1;
    }
    if ((tid & 63) == 0) {
        skey[0][tid >> 6] = key0;
        skey[1][tid >> 6] = key1;
    }
    __syncthreads();

    // threads 0..63 emit row i0, threads 64..127 emit row i1
    if (tid < 128) {
        const int r = tid >> 6;
        const int lane = tid & 63;
        u32 ka = skey[r][0] > skey[r][1] ? skey[r][0] : skey[r][1];
        u32 kb = skey[r][2] > skey[r][3] ? skey[r][2] : skey[r][3];
        u32 kf = ka > kb ? ka : kb;
        const int row = r ? i1 : i0;
        float o = 0.0f;
        if ((kf >> 12) > 0) {
            const int best = 4095 - (int)(kf & 4095u);
            int av = 0;
            #pragma unroll
            for (int k = 0; k < KK; ++k) {
                int c = conn_v[lane * KK + k];
                av |= (tokens[best * BB + c] & 1) << (KK - 1 - k);
            }
            o = table_v[lane * TBL + av];
        }
        out[row * BB + lane] = o;
    }
}

extern "C" void kernel_launch(void* const* d_in, const int* in_sizes, int n_in,
                              void* d_out, int out_size, void* d_ws, size_t ws_size,
                              hipStream_t stream) {
    const int*   tokens     = (const int*)d_in[0];
    const int*   conn_heads = (const int*)d_in[1];
    const float* head_table = (const float*)d_in[2];
    const int*   conn_v     = (const int*)d_in[3];
    const float* table_v    = (const float*)d_in[4];
    float* out = (float*)d_out;

    int* ws = (int*)d_ws;
    u16* A16  = (u16*)ws;                         // S*8 u16 = 8192 ints
    u16* AK16 = (u16*)(ws + 1 * SS * HH / 2);
    u16* P16  = (u16*)(ws + 2 * SS * HH / 2);
    u32* bits = (u32*)(ws + 3 * SS * HH / 2);

    const int total1 = SS * HH + HH * TBLW;   // 16384 + 1024
    precompute_kernel<<<(total1 + 255) / 256, 256, 0, stream>>>(
        tokens, conn_heads, head_table, A16, AK16, P16, bits);
    vote_kernel<<<SS / 2, 256, 0, stream>>>(
        A16, AK16, P16, bits, tokens, conn_v, table_v, out);
}